// Round 9
// baseline (222.490 us; speedup 1.0000x reference)
//
#include <hip/hip_runtime.h>
#include <hip/hip_bf16.h>

typedef __bf16 bf16_t;
typedef __bf16 bf16x8 __attribute__((ext_vector_type(8)));
typedef __bf16 bf16x4 __attribute__((ext_vector_type(4)));
typedef float  f32x4  __attribute__((ext_vector_type(4)));

#define SEQ    2048
#define BATCH  2
#define NHEAD  16
#define HDIM   64
#define DMODEL 1024
#define WIN    256

// async global->LDS, 16B per lane (dest = wave-uniform base + lane*16).
__device__ __forceinline__ void async_load16(const void* g, void* l) {
    __builtin_amdgcn_global_load_lds(
        (const __attribute__((address_space(1))) char*)(uintptr_t)g,
        (__attribute__((address_space(3))) char*)(uintptr_t)l, 16, 0, 0);
}

// ---------------------------------------------------------------------------
// Prep kernel: blocks 0..1023 transpose+cast the 4 weight mats (64x64 tiles,
// float4 reads); blocks 1024..2047 cast x -> bf16 (float4).
// ---------------------------------------------------------------------------
__global__ __launch_bounds__(256) void prep_kernel(
    const float* __restrict__ x, const float* __restrict__ Wq,
    const float* __restrict__ Wk, const float* __restrict__ Wv,
    const float* __restrict__ Wo, bf16_t* __restrict__ xb,
    bf16_t* __restrict__ Wt) {
    const int bid = blockIdx.x, tid = threadIdx.x;
    if (bid < 1024) {
        __shared__ float t64[64][65];
        const int mat = bid >> 8, tile = bid & 255;
        const int k0 = (tile >> 4) * 64, n0 = (tile & 15) * 64;
        const float* W = (mat == 0) ? Wq : (mat == 1) ? Wk : (mat == 2) ? Wv : Wo;
        bf16_t* out = Wt + (size_t)mat * DMODEL * DMODEL;
        const int r = tid >> 4, c4 = tid & 15;
#pragma unroll
        for (int i = 0; i < 4; i++) {
            int krow = i * 16 + r;
            float4 v = *(const float4*)&W[(size_t)(k0 + krow) * DMODEL + n0 + c4 * 4];
            t64[krow][c4 * 4 + 0] = v.x; t64[krow][c4 * 4 + 1] = v.y;
            t64[krow][c4 * 4 + 2] = v.z; t64[krow][c4 * 4 + 3] = v.w;
        }
        __syncthreads();
#pragma unroll
        for (int j = 0; j < 4; j++) {
            int nrow = j * 16 + r;
            bf16x4 o;
#pragma unroll
            for (int q = 0; q < 4; q++) o[q] = (bf16_t)t64[c4 * 4 + q][nrow];
            *(bf16x4*)&out[(size_t)(n0 + nrow) * DMODEL + k0 + c4 * 4] = o;
        }
    } else {
        const int cb = bid - 1024;
#pragma unroll
        for (int it = 0; it < 4; it++) {
            int i = (cb * 4 + it) * 256 + tid;
            float4 v = ((const float4*)x)[i];
            bf16x4 o;
            o[0] = (bf16_t)v.x; o[1] = (bf16_t)v.y; o[2] = (bf16_t)v.z; o[3] = (bf16_t)v.w;
            ((bf16x4*)xb)[i] = o;
        }
    }
}

// ---------------------------------------------------------------------------
// QKV GEMM: 256x192 tile, BK=64, 8 waves (2M x 4N), 256 blocks (all CUs),
// safe 2-phase double-buffer. Epilogue: Q scaled by 1/8*log2e -> Qb[B,H,S,64];
// K -> Kb[B,H,S,64]; V written DIRECTLY TRANSPOSED -> Vt[B,H,64,S].
// ---------------------------------------------------------------------------
__global__ __launch_bounds__(512) void gemm_qkv_kernel(
    const bf16_t* __restrict__ A, const bf16_t* __restrict__ Bt,
    bf16_t* __restrict__ Qb, bf16_t* __restrict__ Kb, bf16_t* __restrict__ Vt) {
    __shared__ __attribute__((aligned(16))) bf16_t smem[2][(256 + 192) * 64];
    const int tid = threadIdx.x;
    const int wave = tid >> 6, lane = tid & 63, quad = lane >> 4, l15 = lane & 15;
    const int wm = wave >> 2, wn = wave & 3;
    const int id = blockIdx.x, xcd = id & 7, tt = id >> 3;
    const int gidx = xcd * 32 + tt;                 // 256 blocks, bijective
    const int m0 = (gidx & 15) * 256, n0 = (gidx >> 4) * 192;

    const int cth = (tid & 7) ^ ((tid >> 3) & 7);   // swizzled source chunk
    const int rA = tid >> 3;                        // row-in-group 0..63

    auto stage = [&](int tile, int buf) {
#pragma unroll
        for (int gr = 0; gr < 4; ++gr)              // A: 256 rows
            async_load16(A + (size_t)(m0 + gr * 64 + rA) * 1024 + tile * 64 + cth * 8,
                         (char*)&smem[buf][0] + (size_t)(gr * 512 + tid) * 16);
#pragma unroll
        for (int gr = 0; gr < 3; ++gr)              // B: 192 rows
            async_load16(Bt + (size_t)(n0 + gr * 64 + rA) * 1024 + tile * 64 + cth * 8,
                         (char*)&smem[buf][256 * 64] + (size_t)(gr * 512 + tid) * 16);
    };

    const int swz  = l15 & 7;
    const int rowA = wm * 128 + l15;
    const int rowB = wn * 48 + l15;                 // 48*wn ≡ 0 mod 8 -> swz ok

    f32x4 acc[8][3] = {};

    stage(0, 0);
    __syncthreads();
    int cur = 0;
#pragma unroll 1
    for (int t = 0; t < 16; ++t) {
        if (t + 1 < 16) stage(t + 1, cur ^ 1);      // loads fly under compute
        const bf16_t* as = &smem[cur][0];
        const bf16_t* bs = &smem[cur][256 * 64];
#pragma unroll
        for (int kk = 0; kk < 2; ++kk) {
            const int chk = ((kk * 4 + quad) ^ swz) * 8;
            bf16x8 am[8], bn[3];
#pragma unroll
            for (int i = 0; i < 8; i++)
                am[i] = *(const bf16x8*)&as[(rowA + i * 16) * 64 + chk];
#pragma unroll
            for (int j = 0; j < 3; j++)
                bn[j] = *(const bf16x8*)&bs[(rowB + j * 16) * 64 + chk];
#pragma unroll
            for (int i = 0; i < 8; i++)
#pragma unroll
                for (int j = 0; j < 3; j++)
                    acc[i][j] = __builtin_amdgcn_mfma_f32_16x16x32_bf16(am[i], bn[j], acc[i][j], 0, 0, 0);
        }
        __syncthreads();                            // vmcnt(0)+barrier drain
        cur ^= 1;
    }

#pragma unroll
    for (int i = 0; i < 8; i++)
#pragma unroll
        for (int j = 0; j < 3; j++) {
            const int mg0 = m0 + wm * 128 + i * 16 + quad * 4;   // r=0, 4-aligned
            const int ng  = n0 + wn * 48 + j * 16 + l15;
            const int sel = ng >> 10, nl = ng & 1023, h = nl >> 6, d = nl & 63;
            const int b = mg0 >> 11, s0 = mg0 & 2047;            // const over r
            if (sel == 2) {
                // V transposed: Vt[((b*16+h)*64+d)*2048 + s0 .. +3]
                bf16x4 o;
#pragma unroll
                for (int r = 0; r < 4; r++) o[r] = (bf16_t)acc[i][j][r];
                *(bf16x4*)&Vt[((size_t)((b * NHEAD + h) * HDIM + d)) * SEQ + s0] = o;
            } else {
#pragma unroll
                for (int r = 0; r < 4; r++) {
                    float v = acc[i][j][r];
                    size_t idx = ((size_t)((b * NHEAD + h) * SEQ) + s0 + r) * HDIM + d;
                    if (sel == 0) Qb[idx] = (bf16_t)(v * 0.18033688011112042f);
                    else          Kb[idx] = (bf16_t)v;
                }
            }
        }
}

// ---------------------------------------------------------------------------
// Out GEMM: 64x128 tile, 512 blocks (2+ blocks/CU; 48 KiB LDS). Proven
// 2-phase dbuf structure.
// ---------------------------------------------------------------------------
__global__ __launch_bounds__(256) void gemm_out_kernel(
    const bf16_t* __restrict__ A, const bf16_t* __restrict__ Bt,
    float* __restrict__ Out, const float* __restrict__ bo) {
    __shared__ __attribute__((aligned(16))) bf16_t As[2][64 * 64];
    __shared__ __attribute__((aligned(16))) bf16_t Bs[2][128 * 64];
    const int tid = threadIdx.x;
    const int wn = tid >> 6, lane = tid & 63, quad = lane >> 4, l15 = lane & 15;
    const int id = blockIdx.x, xcd = id & 7, mt = id >> 3;
    const int m0 = mt * 64, n0 = xcd * 128;        // M=4096(64x64) x N=1024(8x128)

    auto stage = [&](int kt, int buf) {
#pragma unroll
        for (int i = 0; i < 2; i++) {
            int v = tid + i * 256;
            int row = v >> 3, c = (v & 7) ^ (row & 7);
            async_load16(A + (size_t)(m0 + row) * 1024 + kt * 64 + c * 8,
                         (char*)&As[buf][0] + (size_t)v * 16);
        }
#pragma unroll
        for (int i = 0; i < 4; i++) {
            int v = tid + i * 256;
            int row = v >> 3, c = (v & 7) ^ (row & 7);
            async_load16(Bt + (size_t)(n0 + row) * 1024 + kt * 64 + c * 8,
                         (char*)&Bs[buf][0] + (size_t)v * 16);
        }
    };

    f32x4 acc[4][2] = {};
    stage(0, 0);
    __syncthreads();
    int cur = 0;
    for (int kt = 0; kt < 16; ++kt) {
        if (kt + 1 < 16) stage(kt + 1, cur ^ 1);
#pragma unroll
        for (int kk = 0; kk < 64; kk += 32) {
            bf16x8 am[4], bn[2];
#pragma unroll
            for (int i = 0; i < 4; i++) {
                int row = i * 16 + l15;
                int ch = ((kk >> 3) + quad) ^ (row & 7);
                am[i] = *(const bf16x8*)&As[cur][row * 64 + ch * 8];
            }
#pragma unroll
            for (int j = 0; j < 2; j++) {
                int row = wn * 32 + j * 16 + l15;
                int ch = ((kk >> 3) + quad) ^ (row & 7);
                bn[j] = *(const bf16x8*)&Bs[cur][row * 64 + ch * 8];
            }
#pragma unroll
            for (int i = 0; i < 4; i++)
#pragma unroll
                for (int j = 0; j < 2; j++)
                    acc[i][j] = __builtin_amdgcn_mfma_f32_16x16x32_bf16(am[i], bn[j], acc[i][j], 0, 0, 0);
        }
        __syncthreads();                           // vmcnt(0)+barrier drain
        cur ^= 1;
    }

#pragma unroll
    for (int i = 0; i < 4; i++)
#pragma unroll
        for (int j = 0; j < 2; j++)
#pragma unroll
            for (int r = 0; r < 4; r++) {
                int mg = m0 + i * 16 + quad * 4 + r;
                int ng = n0 + wn * 32 + j * 16 + l15;
                Out[(size_t)mg * DMODEL + ng] = acc[i][j][r] + bo[ng];
            }
}

// ---------------------------------------------------------------------------
// Attention v9: BARRIER-FREE. 1024 blocks x 256 threads; 4 waves per block,
// each wave owns 16 q (block = one 64-aligned q-tile). K and V fragments are
// read DIRECTLY from global into registers (no LDS staging, no __syncthreads,
// no cross-wave sharing -> race-free by construction). The 4 waves share the
// same 9-tile window, so tile reads hit L1 (32KB/CU) after first touch; K
// reads are perfectly coalesced (2KB contiguous per c-step). P round-trip
// uses a per-wave private LDS buffer (same-wave ds_write->ds_read; compiler
// inserts lgkmcnt). Swapped QK^T (S^T), exp2, in-register psum + shfl.
// ---------------------------------------------------------------------------
__global__ __launch_bounds__(256) void attn_kernel(
    const bf16_t* __restrict__ Qb, const bf16_t* __restrict__ Kb,
    const bf16_t* __restrict__ Vt, bf16_t* __restrict__ ctx) {
    __shared__ __attribute__((aligned(16))) bf16_t Plds[4][16][72];
    const int tid = threadIdx.x;
    const int wave = tid >> 6, lane = tid & 63, quad = lane >> 4, l15 = lane & 15;

    const int id = blockIdx.x;                      // 1024 blocks, XCD-swizzled
    const int task = (id & 7) * 128 + (id >> 3);
    const int b = task >> 9, h = (task >> 5) & 15, Q0 = (task & 31) << 6;
    const int qbase = Q0 + wave * 16;
    const int base_t = Q0 >> 6;

    const bf16_t* Qp = Qb + (size_t)(b * NHEAD + h) * SEQ * HDIM;
    const bf16_t* Kp = Kb + (size_t)(b * NHEAD + h) * SEQ * HDIM;
    const bf16_t* Vp = Vt + (size_t)(b * NHEAD + h) * HDIM * SEQ;

    bf16x8 qa0 = *(const bf16x8*)(Qp + (size_t)(qbase + l15) * HDIM + quad * 8);
    bf16x8 qa1 = *(const bf16x8*)(Qp + (size_t)(qbase + l15) * HDIM + 32 + quad * 8);

    f32x4 O[4] = {};
    float psum = 0.0f;

    const int bt0 = (base_t - 4 > 0) ? base_t - 4 : 0;
    const int bt1 = (base_t + 4 < SEQ / 64 - 1) ? base_t + 4 : SEQ / 64 - 1;

#pragma unroll 1
    for (int kt = bt0; kt <= bt1; kt++) {
        const int k0 = kt * 64;
        const int dt = kt - base_t;
        f32x4 st[4];
#pragma unroll
        for (int c = 0; c < 4; c++) {
            int row = c * 16 + l15;
            // coalesced: 64 lanes cover rows c*16..c*16+15 x 128B contiguous
            bf16x8 kb0 = *(const bf16x8*)(Kp + (size_t)(k0 + row) * HDIM + quad * 8);
            bf16x8 kb1 = *(const bf16x8*)(Kp + (size_t)(k0 + row) * HDIM + 32 + quad * 8);
            f32x4 a = {};
            a = __builtin_amdgcn_mfma_f32_16x16x32_bf16(kb0, qa0, a, 0, 0, 0);  // S^T
            a = __builtin_amdgcn_mfma_f32_16x16x32_bf16(kb1, qa1, a, 0, 0, 0);
            st[c] = a;
        }
        const bool edge = (dt == -4 || dt == 4);
        const int q = qbase + l15;
#pragma unroll
        for (int c = 0; c < 4; c++) {
            bf16x4 pk;
#pragma unroll
            for (int r = 0; r < 4; r++) {
                float sv = st[c][r];
                if (edge) {
                    int k = k0 + c * 16 + quad * 4 + r;
                    int dd = q - k; dd = (dd < 0) ? -dd : dd;
                    if (dd > WIN) sv = -1e30f;
                }
                pk[r] = (bf16_t)exp2f(sv);
                psum += (float)pk[r];              // bf16-rounded, fp32 accum
            }
            *(bf16x4*)&Plds[wave][l15][c * 16 + quad * 4] = pk;
        }
        bf16x8 pa0 = *(const bf16x8*)&Plds[wave][l15][quad * 8];
        bf16x8 pa1 = *(const bf16x8*)&Plds[wave][l15][32 + quad * 8];
#pragma unroll
        for (int d = 0; d < 4; d++) {
            int row = d * 16 + l15;
            bf16x8 vb0 = *(const bf16x8*)(Vp + (size_t)row * SEQ + k0 + quad * 8);
            bf16x8 vb1 = *(const bf16x8*)(Vp + (size_t)row * SEQ + k0 + 32 + quad * 8);
            O[d] = __builtin_amdgcn_mfma_f32_16x16x32_bf16(pa0, vb0, O[d], 0, 0, 0);
            O[d] = __builtin_amdgcn_mfma_f32_16x16x32_bf16(pa1, vb1, O[d], 0, 0, 0);
        }
    }

    psum += __shfl_xor(psum, 16, 64);
    psum += __shfl_xor(psum, 32, 64);               // full row-sum for q=qbase+l15
#pragma unroll
    for (int r = 0; r < 4; r++) {
        // O's row q = qbase+quad*4+r lives in lanes with l15' = quad*4+r
        float s_q = __shfl(psum, (quad << 4) | (quad * 4 + r), 64);
        float inv = 1.0f / s_q;
        int i = qbase + quad * 4 + r;
#pragma unroll
        for (int d = 0; d < 4; d++) {
            float v = O[d][r] * inv;
            ctx[((size_t)(b * SEQ + i)) * DMODEL + h * HDIM + d * 16 + l15] = (bf16_t)v;
        }
    }
}

// ---------------------------------------------------------------------------
extern "C" void kernel_launch(void* const* d_in, const int* in_sizes, int n_in,
                              void* d_out, int out_size, void* d_ws, size_t ws_size,
                              hipStream_t stream) {
    const float* x  = (const float*)d_in[0];
    const float* Wq = (const float*)d_in[1];
    const float* Wk = (const float*)d_in[2];
    const float* Wv = (const float*)d_in[3];
    const float* Wo = (const float*)d_in[4];
    const float* bo = (const float*)d_in[5];
    float* out = (float*)d_out;

    const size_t MTOK = (size_t)BATCH * SEQ;          // 4096
    bf16_t* xb  = (bf16_t*)d_ws;                      // 4096*1024
    bf16_t* Wt  = xb + MTOK * DMODEL;                 // 4*1024*1024
    bf16_t* Qb  = Wt + (size_t)4 * DMODEL * DMODEL;   // [B,H,S,64]
    bf16_t* Kb  = Qb + MTOK * DMODEL;                 // [B,H,S,64]
    bf16_t* Vt  = Kb + MTOK * DMODEL;                 // [B,H,64,S] (written by QKV)
    bf16_t* ctx = Vt + MTOK * DMODEL;                 // [4096][1024]

    prep_kernel<<<dim3(2048), dim3(256), 0, stream>>>(x, Wq, Wk, Wv, Wo, xb, Wt);
    // QKV: M=4096, N=3072, K=1024; 256 blocks of 512 (256x192 tiles, 2-phase)
    gemm_qkv_kernel<<<dim3(256), dim3(512), 0, stream>>>(xb, Wt, Qb, Kb, Vt);
    // attn: 1024 blocks of 256 (64 q per block, barrier-free direct-global)
    attn_kernel<<<dim3(1024), dim3(256), 0, stream>>>(Qb, Kb, Vt, ctx);
    // Out: M=4096, N=1024, K=1024; 512 blocks of 256 (64x128, 2-phase dbuf)
    gemm_out_kernel<<<dim3(512), dim3(256), 0, stream>>>(
        ctx, Wt + (size_t)3 * DMODEL * DMODEL, out, bo);
}

// Round 11
// 155.926 us; speedup vs baseline: 1.4269x; 1.4269x over previous
//
#include <hip/hip_runtime.h>
#include <hip/hip_bf16.h>

typedef __bf16 bf16_t;
typedef __bf16 bf16x8 __attribute__((ext_vector_type(8)));
typedef __bf16 bf16x4 __attribute__((ext_vector_type(4)));
typedef float  f32x4  __attribute__((ext_vector_type(4)));

#define SEQ    2048
#define BATCH  2
#define NHEAD  16
#define HDIM   64
#define DMODEL 1024
#define WIN    256

// async global->LDS, 16B per lane (dest = wave-uniform base + lane*16).
__device__ __forceinline__ void async_load16(const void* g, void* l) {
    __builtin_amdgcn_global_load_lds(
        (const __attribute__((address_space(1))) char*)(uintptr_t)g,
        (__attribute__((address_space(3))) char*)(uintptr_t)l, 16, 0, 0);
}

// ---------------------------------------------------------------------------
// Prep kernel: blocks 0..1023 transpose+cast the 4 weight mats (64x64 tiles,
// float4 reads); blocks 1024..2047 cast x -> bf16 (float4).
// ---------------------------------------------------------------------------
__global__ __launch_bounds__(256) void prep_kernel(
    const float* __restrict__ x, const float* __restrict__ Wq,
    const float* __restrict__ Wk, const float* __restrict__ Wv,
    const float* __restrict__ Wo, bf16_t* __restrict__ xb,
    bf16_t* __restrict__ Wt) {
    const int bid = blockIdx.x, tid = threadIdx.x;
    if (bid < 1024) {
        __shared__ float t64[64][65];
        const int mat = bid >> 8, tile = bid & 255;
        const int k0 = (tile >> 4) * 64, n0 = (tile & 15) * 64;
        const float* W = (mat == 0) ? Wq : (mat == 1) ? Wk : (mat == 2) ? Wv : Wo;
        bf16_t* out = Wt + (size_t)mat * DMODEL * DMODEL;
        const int r = tid >> 4, c4 = tid & 15;
#pragma unroll
        for (int i = 0; i < 4; i++) {
            int krow = i * 16 + r;
            float4 v = *(const float4*)&W[(size_t)(k0 + krow) * DMODEL + n0 + c4 * 4];
            t64[krow][c4 * 4 + 0] = v.x; t64[krow][c4 * 4 + 1] = v.y;
            t64[krow][c4 * 4 + 2] = v.z; t64[krow][c4 * 4 + 3] = v.w;
        }
        __syncthreads();
#pragma unroll
        for (int j = 0; j < 4; j++) {
            int nrow = j * 16 + r;
            bf16x4 o;
#pragma unroll
            for (int q = 0; q < 4; q++) o[q] = (bf16_t)t64[c4 * 4 + q][nrow];
            *(bf16x4*)&out[(size_t)(n0 + nrow) * DMODEL + k0 + c4 * 4] = o;
        }
    } else {
        const int cb = bid - 1024;
#pragma unroll
        for (int it = 0; it < 4; it++) {
            int i = (cb * 4 + it) * 256 + tid;
            float4 v = ((const float4*)x)[i];
            bf16x4 o;
            o[0] = (bf16_t)v.x; o[1] = (bf16_t)v.y; o[2] = (bf16_t)v.z; o[3] = (bf16_t)v.w;
            ((bf16x4*)xb)[i] = o;
        }
    }
}

// ---------------------------------------------------------------------------
// QKV GEMM: 256x192 tile, BK=64, 8 waves (2M x 4N), 256 blocks (all CUs),
// safe 2-phase double-buffer. Epilogue: Q scaled by 1/8*log2e -> Qb[B,H,S,64];
// K -> Kb[B,H,S,64]; V written DIRECTLY TRANSPOSED -> Vt[B,H,64,S].
// ---------------------------------------------------------------------------
__global__ __launch_bounds__(512) void gemm_qkv_kernel(
    const bf16_t* __restrict__ A, const bf16_t* __restrict__ Bt,
    bf16_t* __restrict__ Qb, bf16_t* __restrict__ Kb, bf16_t* __restrict__ Vt) {
    __shared__ __attribute__((aligned(16))) bf16_t smem[2][(256 + 192) * 64];
    const int tid = threadIdx.x;
    const int wave = tid >> 6, lane = tid & 63, quad = lane >> 4, l15 = lane & 15;
    const int wm = wave >> 2, wn = wave & 3;
    const int id = blockIdx.x, xcd = id & 7, tt = id >> 3;
    const int gidx = xcd * 32 + tt;                 // 256 blocks, bijective
    const int m0 = (gidx & 15) * 256, n0 = (gidx >> 4) * 192;

    const int cth = (tid & 7) ^ ((tid >> 3) & 7);   // swizzled source chunk
    const int rA = tid >> 3;                        // row-in-group 0..63

    auto stage = [&](int tile, int buf) {
#pragma unroll
        for (int gr = 0; gr < 4; ++gr)              // A: 256 rows
            async_load16(A + (size_t)(m0 + gr * 64 + rA) * 1024 + tile * 64 + cth * 8,
                         (char*)&smem[buf][0] + (size_t)(gr * 512 + tid) * 16);
#pragma unroll
        for (int gr = 0; gr < 3; ++gr)              // B: 192 rows
            async_load16(Bt + (size_t)(n0 + gr * 64 + rA) * 1024 + tile * 64 + cth * 8,
                         (char*)&smem[buf][256 * 64] + (size_t)(gr * 512 + tid) * 16);
    };

    const int swz  = l15 & 7;
    const int rowA = wm * 128 + l15;
    const int rowB = wn * 48 + l15;                 // 48*wn ≡ 0 mod 8 -> swz ok

    f32x4 acc[8][3] = {};

    stage(0, 0);
    __syncthreads();
    int cur = 0;
#pragma unroll 1
    for (int t = 0; t < 16; ++t) {
        if (t + 1 < 16) stage(t + 1, cur ^ 1);      // loads fly under compute
        const bf16_t* as = &smem[cur][0];
        const bf16_t* bs = &smem[cur][256 * 64];
#pragma unroll
        for (int kk = 0; kk < 2; ++kk) {
            const int chk = ((kk * 4 + quad) ^ swz) * 8;
            bf16x8 am[8], bn[3];
#pragma unroll
            for (int i = 0; i < 8; i++)
                am[i] = *(const bf16x8*)&as[(rowA + i * 16) * 64 + chk];
#pragma unroll
            for (int j = 0; j < 3; j++)
                bn[j] = *(const bf16x8*)&bs[(rowB + j * 16) * 64 + chk];
#pragma unroll
            for (int i = 0; i < 8; i++)
#pragma unroll
                for (int j = 0; j < 3; j++)
                    acc[i][j] = __builtin_amdgcn_mfma_f32_16x16x32_bf16(am[i], bn[j], acc[i][j], 0, 0, 0);
        }
        __syncthreads();                            // vmcnt(0)+barrier drain
        cur ^= 1;
    }

#pragma unroll
    for (int i = 0; i < 8; i++)
#pragma unroll
        for (int j = 0; j < 3; j++) {
            const int mg0 = m0 + wm * 128 + i * 16 + quad * 4;   // r=0, 4-aligned
            const int ng  = n0 + wn * 48 + j * 16 + l15;
            const int sel = ng >> 10, nl = ng & 1023, h = nl >> 6, d = nl & 63;
            const int b = mg0 >> 11, s0 = mg0 & 2047;            // const over r
            if (sel == 2) {
                // V transposed: Vt[((b*16+h)*64+d)*2048 + s0 .. +3]
                bf16x4 o;
#pragma unroll
                for (int r = 0; r < 4; r++) o[r] = (bf16_t)acc[i][j][r];
                *(bf16x4*)&Vt[((size_t)((b * NHEAD + h) * HDIM + d)) * SEQ + s0] = o;
            } else {
#pragma unroll
                for (int r = 0; r < 4; r++) {
                    float v = acc[i][j][r];
                    size_t idx = ((size_t)((b * NHEAD + h) * SEQ) + s0 + r) * HDIM + d;
                    if (sel == 0) Qb[idx] = (bf16_t)(v * 0.18033688011112042f);
                    else          Kb[idx] = (bf16_t)v;
                }
            }
        }
}

// ---------------------------------------------------------------------------
// Out GEMM: 64x128 tile, 512 blocks (2+ blocks/CU; 48 KiB LDS). Proven
// 2-phase dbuf structure.
// ---------------------------------------------------------------------------
__global__ __launch_bounds__(256) void gemm_out_kernel(
    const bf16_t* __restrict__ A, const bf16_t* __restrict__ Bt,
    float* __restrict__ Out, const float* __restrict__ bo) {
    __shared__ __attribute__((aligned(16))) bf16_t As[2][64 * 64];
    __shared__ __attribute__((aligned(16))) bf16_t Bs[2][128 * 64];
    const int tid = threadIdx.x;
    const int wn = tid >> 6, lane = tid & 63, quad = lane >> 4, l15 = lane & 15;
    const int id = blockIdx.x, xcd = id & 7, mt = id >> 3;
    const int m0 = mt * 64, n0 = xcd * 128;        // M=4096(64x64) x N=1024(8x128)

    auto stage = [&](int kt, int buf) {
#pragma unroll
        for (int i = 0; i < 2; i++) {
            int v = tid + i * 256;
            int row = v >> 3, c = (v & 7) ^ (row & 7);
            async_load16(A + (size_t)(m0 + row) * 1024 + kt * 64 + c * 8,
                         (char*)&As[buf][0] + (size_t)v * 16);
        }
#pragma unroll
        for (int i = 0; i < 4; i++) {
            int v = tid + i * 256;
            int row = v >> 3, c = (v & 7) ^ (row & 7);
            async_load16(Bt + (size_t)(n0 + row) * 1024 + kt * 64 + c * 8,
                         (char*)&Bs[buf][0] + (size_t)v * 16);
        }
    };

    f32x4 acc[4][2] = {};
    stage(0, 0);
    __syncthreads();
    int cur = 0;
    for (int kt = 0; kt < 16; ++kt) {
        if (kt + 1 < 16) stage(kt + 1, cur ^ 1);
#pragma unroll
        for (int kk = 0; kk < 64; kk += 32) {
            bf16x8 am[4], bn[2];
#pragma unroll
            for (int i = 0; i < 4; i++) {
                int row = i * 16 + l15;
                int ch = ((kk >> 3) + quad) ^ (row & 7);
                am[i] = *(const bf16x8*)&As[cur][row * 64 + ch * 8];
            }
#pragma unroll
            for (int j = 0; j < 2; j++) {
                int row = wn * 32 + j * 16 + l15;
                int ch = ((kk >> 3) + quad) ^ (row & 7);
                bn[j] = *(const bf16x8*)&Bs[cur][row * 64 + ch * 8];
            }
#pragma unroll
            for (int i = 0; i < 4; i++)
#pragma unroll
                for (int j = 0; j < 2; j++)
                    acc[i][j] = __builtin_amdgcn_mfma_f32_16x16x32_bf16(am[i], bn[j], acc[i][j], 0, 0, 0);
        }
        __syncthreads();                           // vmcnt(0)+barrier drain
        cur ^= 1;
    }

#pragma unroll
    for (int i = 0; i < 4; i++)
#pragma unroll
        for (int j = 0; j < 2; j++)
#pragma unroll
            for (int r = 0; r < 4; r++) {
                int mg = m0 + i * 16 + quad * 4 + r;
                int ng = n0 + wn * 32 + j * 16 + l15;
                Out[(size_t)mg * DMODEL + ng] = acc[i][j][r] + bo[ng];
            }
}

// ---------------------------------------------------------------------------
// Attention v6 (exact best-known, 157.6 us at R6): 512 threads, 128 q per
// block, 16 q per wave; block stages the 10-tile union window, each wave
// computes its 9 in-window tiles. Swapped QK^T (S^T), libm exp2f, gload_lds
// dbuf, 1 __syncthreads/tile, in-register row-sum + shfl reduce.
// ---------------------------------------------------------------------------
__global__ __launch_bounds__(512) void attn_kernel(
    const bf16_t* __restrict__ Qb, const bf16_t* __restrict__ Kb,
    const bf16_t* __restrict__ Vt, bf16_t* __restrict__ ctx) {
    __shared__ __attribute__((aligned(16))) bf16_t Ks[2][64 * 64];
    __shared__ __attribute__((aligned(16))) bf16_t Vs[2][64 * 64];
    __shared__ __attribute__((aligned(16))) bf16_t Plds[8][16][72];
    const int tid = threadIdx.x;
    const int wave = tid >> 6, lane = tid & 63, quad = lane >> 4, l15 = lane & 15;

    const int id = blockIdx.x;
    const int task = (id & 7) * 64 + (id >> 3);     // 512 blocks, XCD-swizzled
    const int b = task >> 8, h = (task >> 4) & 15, Q0 = (task & 15) << 7;
    const int qbase = Q0 + wave * 16;
    const int wqt = (Q0 >> 6) + (wave >> 2);        // this wave's 64-aligned q-tile

    const bf16_t* Qp = Qb + (size_t)(b * NHEAD + h) * SEQ * HDIM;
    const bf16_t* Kp = Kb + (size_t)(b * NHEAD + h) * SEQ * HDIM;
    const bf16_t* Vp = Vt + (size_t)(b * NHEAD + h) * HDIM * SEQ;

    bf16x8 qa0 = *(const bf16x8*)(Qp + (size_t)(qbase + l15) * HDIM + quad * 8);
    bf16x8 qa1 = *(const bf16x8*)(Qp + (size_t)(qbase + l15) * HDIM + 32 + quad * 8);

    f32x4 O[4] = {};
    float psum = 0.0f;

    const int base_t = Q0 >> 6;
    const int bt0 = (base_t - 4 > 0) ? base_t - 4 : 0;
    const int bt1 = (base_t + 5 < SEQ / 64 - 1) ? base_t + 5 : SEQ / 64 - 1;

    auto stage = [&](int kt, int buf) {
        const int k0 = kt * 64;
        int v = tid;                                // 512 chunks of 16B each
        int row = v >> 3, c = (v & 7) ^ (row & 7);
        async_load16(Kp + (size_t)(k0 + row) * HDIM + c * 8, (char*)&Ks[buf][0] + (size_t)v * 16);
        async_load16(Vp + (size_t)row * SEQ + k0 + c * 8, (char*)&Vs[buf][0] + (size_t)v * 16);
    };

    stage(bt0, 0);
    int cb = 0;
    for (int kt = bt0; kt <= bt1; kt++) {
        __syncthreads();
        if (kt < bt1) stage(kt + 1, cb ^ 1);
        const int dt = kt - wqt;
        if (dt >= -4 && dt <= 4) {                  // wave-uniform window check
            const int k0 = kt * 64;
            f32x4 st[4];
#pragma unroll
            for (int c = 0; c < 4; c++) {
                int row = c * 16 + l15;
                bf16x8 kb0 = *(const bf16x8*)&Ks[cb][row * 64 + (quad ^ (row & 7)) * 8];
                bf16x8 kb1 = *(const bf16x8*)&Ks[cb][row * 64 + ((quad + 4) ^ (row & 7)) * 8];
                f32x4 a = {};
                a = __builtin_amdgcn_mfma_f32_16x16x32_bf16(kb0, qa0, a, 0, 0, 0);  // S^T
                a = __builtin_amdgcn_mfma_f32_16x16x32_bf16(kb1, qa1, a, 0, 0, 0);
                st[c] = a;
            }
            const bool edge = (dt == -4 || dt == 4);
            const int q = qbase + l15;
#pragma unroll
            for (int c = 0; c < 4; c++) {
                bf16x4 pk;
#pragma unroll
                for (int r = 0; r < 4; r++) {
                    float sv = st[c][r];
                    if (edge) {
                        int k = k0 + c * 16 + quad * 4 + r;
                        int dd = q - k; dd = (dd < 0) ? -dd : dd;
                        if (dd > WIN) sv = -1e30f;
                    }
                    pk[r] = (bf16_t)exp2f(sv);
                    psum += (float)pk[r];          // bf16-rounded, fp32 accum
                }
                *(bf16x4*)&Plds[wave][l15][c * 16 + quad * 4] = pk;
            }
            bf16x8 pa0 = *(const bf16x8*)&Plds[wave][l15][quad * 8];
            bf16x8 pa1 = *(const bf16x8*)&Plds[wave][l15][32 + quad * 8];
#pragma unroll
            for (int d = 0; d < 4; d++) {
                int row = d * 16 + l15;
                bf16x8 vb0 = *(const bf16x8*)&Vs[cb][row * 64 + (quad ^ (row & 7)) * 8];
                bf16x8 vb1 = *(const bf16x8*)&Vs[cb][row * 64 + ((quad + 4) ^ (row & 7)) * 8];
                O[d] = __builtin_amdgcn_mfma_f32_16x16x32_bf16(pa0, vb0, O[d], 0, 0, 0);
                O[d] = __builtin_amdgcn_mfma_f32_16x16x32_bf16(pa1, vb1, O[d], 0, 0, 0);
            }
        }
        cb ^= 1;
    }

    // cross-quad reduce: every lane ends with full row-sum for q = qbase+l15
    psum += __shfl_xor(psum, 16, 64);
    psum += __shfl_xor(psum, 32, 64);

#pragma unroll
    for (int r = 0; r < 4; r++) {
        // O's row q = qbase + quad*4 + r lives at source lane l15' = quad*4+r
        float s_q = __shfl(psum, (quad << 4) | (quad * 4 + r), 64);
        float inv = 1.0f / s_q;
        int i = qbase + quad * 4 + r;
#pragma unroll
        for (int d = 0; d < 4; d++) {
            float v = O[d][r] * inv;
            ctx[((size_t)(b * SEQ + i)) * DMODEL + h * HDIM + d * 16 + l15] = (bf16_t)v;
        }
    }
}

// ---------------------------------------------------------------------------
extern "C" void kernel_launch(void* const* d_in, const int* in_sizes, int n_in,
                              void* d_out, int out_size, void* d_ws, size_t ws_size,
                              hipStream_t stream) {
    const float* x  = (const float*)d_in[0];
    const float* Wq = (const float*)d_in[1];
    const float* Wk = (const float*)d_in[2];
    const float* Wv = (const float*)d_in[3];
    const float* Wo = (const float*)d_in[4];
    const float* bo = (const float*)d_in[5];
    float* out = (float*)d_out;

    const size_t MTOK = (size_t)BATCH * SEQ;          // 4096
    bf16_t* xb  = (bf16_t*)d_ws;                      // 4096*1024
    bf16_t* Wt  = xb + MTOK * DMODEL;                 // 4*1024*1024
    bf16_t* Qb  = Wt + (size_t)4 * DMODEL * DMODEL;   // [B,H,S,64]
    bf16_t* Kb  = Qb + MTOK * DMODEL;                 // [B,H,S,64]
    bf16_t* Vt  = Kb + MTOK * DMODEL;                 // [B,H,64,S] (written by QKV)
    bf16_t* ctx = Vt + MTOK * DMODEL;                 // [4096][1024]

    prep_kernel<<<dim3(2048), dim3(256), 0, stream>>>(x, Wq, Wk, Wv, Wo, xb, Wt);
    // QKV: M=4096, N=3072, K=1024; 256 blocks of 512 (256x192 tiles, 2-phase)
    gemm_qkv_kernel<<<dim3(256), dim3(512), 0, stream>>>(xb, Wt, Qb, Kb, Vt);
    // attn: 512 blocks of 512 (128 q per block, v6 structure)
    attn_kernel<<<dim3(512), dim3(512), 0, stream>>>(Qb, Kb, Vt, ctx);
    // Out: M=4096, N=1024, K=1024; 512 blocks of 256 (64x128, 2-phase dbuf)
    gemm_out_kernel<<<dim3(512), dim3(256), 0, stream>>>(
        ctx, Wt + (size_t)3 * DMODEL * DMODEL, out, bo);
}